// Round 12
// baseline (249.317 us; speedup 1.0000x reference)
//
#include <hip/hip_runtime.h>

// B = in_sizes[0]/840, L=40, A=21. One thread per row, ONE WAVE PER BLOCK
// (LDS wave-private, ZERO barriers; fence discipline + in-order DS = R4's
// proven-correct sync). CPOS=4: 336-B per-row segments -> FETCH 1.06x ideal
// (measured R8). Register staging (compiler-managed waitcnt — avoids the
// global_load_lds LDS-DMA conservative vmcnt(0) suspected in R10).
// Register budget sized for the 124-VGPR cap hipcc applies to 64-thread
// blocks (R8/R9 lesson): single 84-VGPR reg buffer + 21 goff + misc ~ 120.
#define LPOS 40
#define AA   21
#define ROWF (LPOS*AA)        // 840 floats per row
#define ROW4 (ROWF/4)         // 210 float4 per row
#define CPOS 4
#define CF   (CPOS*AA)        // 84 floats per row-chunk
#define CF4  (CF/4)           // 21 float4 per row-chunk
#define NCH  (LPOS/CPOS)      // 10 bodies
#define NTHR 64               // one wave per block

// Compiler-only fence: orders memory ops across the staging transpose
// (single-thread alias analysis would otherwise hoist next body's ds_reads
// above this body's ds_writes — the R2/R3 bug). HW per-wave DS is in-order.
#define FENCE() asm volatile("" ::: "memory")

__global__ __launch_bounds__(NTHR) void cm_kernel(
    const float* __restrict__ x,
    const float* __restrict__ vg,
    const float* __restrict__ jg,
    float* __restrict__ out)
{
    __shared__ float4 sbuf[NTHR * CF4];   // 21504 B -> 7 blocks/CU

    const int lane = threadIdx.x;                       // 0..63
    const long long row0 = (long long)blockIdx.x * NTHR;
    const float4* xw4 = (const float4*)x + row0 * ROW4;

    // Per-lane float4 offsets for body 0: flat slot f = lane + 64*i over
    // [64 rows][21 float4]; r = f/21, e = f%21, goff = r*210 + e.
    // Step f += 64  =>  r += 3, e += 1  (wrap: e -= 21, r += 1).
    int goff[CF4];
    {
        int r = lane / AA;
        int e = lane - r * AA;
        int off = r * ROW4 + e;
        #pragma unroll
        for (int i = 0; i < CF4; ++i) {
            goff[i] = off;
            e += 1; off += 3 * ROW4 + 1;
            if (e >= AA) { e -= AA; off += ROW4 - AA; }
        }
    }

    float4 rg[CF4];   // single 84-VGPR staging buffer (depth-1 prefetch)

    // Prologue: body0 -> rg -> LDS; rg <- body1 (stays in flight through
    // body 0's compute; compiler inserts the vmcnt before the LDS write).
    #pragma unroll
    for (int i = 0; i < CF4; ++i) rg[i] = xw4[goff[i]];
    FENCE();
    #pragma unroll
    for (int i = 0; i < CF4; ++i) sbuf[lane + i * 64] = rg[i];
    FENCE();
    #pragma unroll
    for (int i = 0; i < CF4; ++i) rg[i] = xw4[goff[i] + CF4];
    FENCE();

    float run = 1.0f, vsum = 0.0f, jsum = 0.0f;

    for (int k = 0; k < NCH; ++k) {
        // compute body k (4 positions) from LDS; v/j uniform -> s_load
        {
            const float* xs = (const float*)&sbuf[lane * CF4];
            #pragma unroll
            for (int p = 0; p < CPOS; ++p) {
                float m = 0.f, jm = 0.f;
                #pragma unroll
                for (int a = 0; a < AA; ++a) {
                    const float xv = xs[p * AA + a];
                    m  = fmaf(xv, vg[(k * CPOS + p) * AA + a], m);
                    jm = fmaf(xv, jg[(k * CPOS + p) * AA + a], jm);
                }
                run *= m; vsum += run; jsum += jm;
            }
        }
        FENCE();
        if (k + 1 < NCH) {
            // overwrite LDS with body k+1 (WAR safe: reads above issued
            // first, per-wave DS in-order, fences pin program order)
            #pragma unroll
            for (int i = 0; i < CF4; ++i) sbuf[lane + i * 64] = rg[i];
            FENCE();
            if (k + 2 < NCH) {
                #pragma unroll
                for (int i = 0; i < CF4; ++i)
                    rg[i] = xw4[goff[i] + (k + 2) * CF4];
                FENCE();
            }
        }
    }

    ((float2*)out)[row0 + lane] = make_float2(vsum, jsum);  // coalesced 8B
}

extern "C" void kernel_launch(void* const* d_in, const int* in_sizes, int n_in,
                              void* d_out, int out_size, void* d_ws, size_t ws_size,
                              hipStream_t stream) {
    const float* x  = (const float*)d_in[0];
    const float* vg = (const float*)d_in[1];
    const float* jg = (const float*)d_in[2];
    float* out      = (float*)d_out;

    const int B    = in_sizes[0] / ROWF;   // 131072
    const int grid = B / NTHR;             // 2048

    cm_kernel<<<grid, NTHR, 0, stream>>>(x, vg, jg, out);
}

// Round 13
// 93.648 us; speedup vs baseline: 2.6623x; 2.6623x over previous
//
#include <hip/hip_runtime.h>

// B = in_sizes[0]/840, L=40, A=21. One thread per row, ONE WAVE PER BLOCK.
// Minimal-overhead form: global_load_lds staging (zero staging VGPRs -> no
// spill, the R5/R8/R9/R11 killer), SINGLE 21.5 KB LDS buffer -> 7 blocks/CU,
// serial per-body staging (vmcnt(0)) -- budget: 7 waves/CU pace HBM with 3x
// slack even with latency fully exposed, so prefetch depth is not binding
// (consistent with R6/R1). Zero barriers (wave-private LDS). CPOS=4: fetch
// measured ~1.01x ideal (R11). Compute reads vectorize to b128 (stride 21
// float4, 21%8=5 coprime -> even bank-quad spread, conflict-optimal).
#define LPOS 40
#define AA   21
#define ROWF (LPOS*AA)        // 840 floats per row
#define ROW4 (ROWF/4)         // 210 float4 per row
#define CPOS 4
#define CF4  ((CPOS*AA)/4)    // 21 float4 per row-chunk
#define NCH  (LPOS/CPOS)      // 10 bodies
#define NTHR 64               // one wave per block

__global__ __launch_bounds__(NTHR) void cm_kernel(
    const float* __restrict__ x,
    const float* __restrict__ vg,
    const float* __restrict__ jg,
    float* __restrict__ out)
{
    __shared__ float4 sbuf[NTHR * CF4];   // 21504 B: [64 rows][21 float4]

    const int lane = threadIdx.x;                       // 0..63
    const long long row0 = (long long)blockIdx.x * NTHR;
    const float4* xw4 = (const float4*)x + row0 * ROW4;

    // Per-lane float4 offsets for body 0: flat slot f = lane + 64*i over
    // [64 rows][21 float4]; r = f/21, e = f%21, goff = r*210 + e.
    // Step f += 64  =>  r += 3, e += 1  (wrap: e -= 21, r += 1).
    int goff[CF4];
    {
        int r = lane / AA;
        int e = lane - r * AA;
        int off = r * ROW4 + e;
        #pragma unroll
        for (int i = 0; i < CF4; ++i) {
            goff[i] = off;
            e += 1; off += 3 * ROW4 + 1;
            if (e >= AA) { e -= AA; off += ROW4 - AA; }
        }
    }

    float run = 1.0f, vsum = 0.0f, jsum = 0.0f;

    for (int k = 0; k < NCH; ++k) {
        // Stage body k: 21 async global->LDS copies. dst is wave-uniform
        // (+lane*16 implicit in HW -> slot lane + i*64); src is per-lane.
        #pragma unroll
        for (int i = 0; i < CF4; ++i)
            __builtin_amdgcn_global_load_lds(
                (const __attribute__((address_space(1))) void*)
                    (xw4 + goff[i] + k * CF4),
                (__attribute__((address_space(3))) void*)(&sbuf[i * 64]),
                16, 0, 0);
        asm volatile("s_waitcnt vmcnt(0)" ::: "memory");
        __builtin_amdgcn_sched_barrier(0);   // rule #18: no hoist past wait

        // Compute body k (4 positions x 21 aminos) from this lane's row
        // slice; v/j indices wave-uniform -> scalar loads.
        const float* xs = (const float*)&sbuf[lane * CF4];
        #pragma unroll
        for (int p = 0; p < CPOS; ++p) {
            float m = 0.f, jm = 0.f;
            #pragma unroll
            for (int a = 0; a < AA; ++a) {
                const float xv = xs[p * AA + a];
                m  = fmaf(xv, vg[(k * CPOS + p) * AA + a], m);
                jm = fmaf(xv, jg[(k * CPOS + p) * AA + a], jm);
            }
            run *= m; vsum += run; jsum += jm;
        }

        // All ds_reads retired before next body's DMA overwrites the buffer
        // (WAR close-out; wave-private, so program order + DS in-order).
        asm volatile("s_waitcnt lgkmcnt(0)" ::: "memory");
        __builtin_amdgcn_sched_barrier(0);
    }

    ((float2*)out)[row0 + lane] = make_float2(vsum, jsum);  // coalesced 8B
}

extern "C" void kernel_launch(void* const* d_in, const int* in_sizes, int n_in,
                              void* d_out, int out_size, void* d_ws, size_t ws_size,
                              hipStream_t stream) {
    const float* x  = (const float*)d_in[0];
    const float* vg = (const float*)d_in[1];
    const float* jg = (const float*)d_in[2];
    float* out      = (float*)d_out;

    const int B    = in_sizes[0] / ROWF;   // 131072
    const int grid = B / NTHR;             // 2048

    cm_kernel<<<grid, NTHR, 0, stream>>>(x, vg, jg, out);
}